// Round 1
// baseline (438.179 us; speedup 1.0000x reference)
//
#include <hip/hip_runtime.h>
#include <hip/hip_bf16.h>
#include <cstddef>

#define B_ 8
#define H_ 12
#define N_ 2048
#define D_ 64
#define M_ 256
#define BH_ (B_*H_)

static __device__ __forceinline__ float4 ld4(const float* p){ return *(const float4*)p; }

// ---------------- Kernel 1: Qd/Kd/Vd = Dct @ (scaled X) --------------------
// grid (4 mtiles, 96 bh, 3 tensors), 256 threads
__global__ __launch_bounds__(256)
void dct_qkv_kernel(const float* __restrict__ Q, const float* __restrict__ K,
                    const float* __restrict__ V, const float* __restrict__ mask,
                    const float* __restrict__ Dct,
                    float* __restrict__ Qd, float* __restrict__ Kd, float* __restrict__ Vd)
{
    const int mt = blockIdx.x;     // m-tile 0..3 (64 rows of M)
    const int bh = blockIdx.y;     // 0..95
    const int tz = blockIdx.z;     // 0:Q 1:K 2:V
    const int b  = bh / H_;
    const float scale = 0.35355339059327373f;  // 1/sqrt(sqrt(64))

    const float* X; float* Y; float smul; int um;
    if (tz == 0)      { X = Q; Y = Qd; smul = scale; um = 0; }
    else if (tz == 1) { X = K; Y = Kd; smul = scale; um = 1; }
    else              { X = V; Y = Vd; smul = 1.0f;  um = 1; }
    X += (size_t)bh * N_ * D_;
    Y += (size_t)bh * M_ * D_;

    __shared__ float At[16][68];   // At[k][m_local]  (A transposed, padded)
    __shared__ float Bs[16][64];   // Bs[k][d]

    const int tid = threadIdx.x;
    const int tx = tid & 15, ty = tid >> 4;
    const int m0 = mt * 64;

    float acc[4][4] = {};

    for (int kt = 0; kt < N_/16; ++kt) {
        const int k0 = kt * 16;
        __syncthreads();
        // stage A: At[k][m] = Dct[(m0+m)*N + k0+k]
        {
            const int j  = tid & 15;   // k within tile
            const int ib = tid >> 4;   // m base
            #pragma unroll
            for (int rr = 0; rr < 4; ++rr) {
                const int i = ib + rr*16;
                At[j][i] = Dct[(size_t)(m0 + i) * N_ + (k0 + j)];
            }
        }
        // stage B: Bs[k][d] = X[(k0+k)*64 + d] * smul * mask[b, k0+k]
        {
            const float4 t = ld4(X + (size_t)k0 * D_ + tid * 4);
            const int j  = tid >> 4;        // row within tile (tid*4/64)
            const int d0 = (tid & 15) * 4;
            float f = smul;
            if (um) f *= mask[(size_t)b * N_ + k0 + j];
            float4 s; s.x = t.x*f; s.y = t.y*f; s.z = t.z*f; s.w = t.w*f;
            *(float4*)(&Bs[j][d0]) = s;
        }
        __syncthreads();
        #pragma unroll
        for (int k = 0; k < 16; ++k) {
            const float4 av = ld4(&At[k][ty*4]);
            const float4 bv = ld4(&Bs[k][tx*4]);
            const float a[4]  = {av.x, av.y, av.z, av.w};
            const float bb[4] = {bv.x, bv.y, bv.z, bv.w};
            #pragma unroll
            for (int q = 0; q < 4; ++q)
                #pragma unroll
                for (int p = 0; p < 4; ++p)
                    acc[q][p] = fmaf(a[q], bb[p], acc[q][p]);
        }
    }
    #pragma unroll
    for (int q = 0; q < 4; ++q) {
        float4 o; o.x = acc[q][0]; o.y = acc[q][1]; o.z = acc[q][2]; o.w = acc[q][3];
        *(float4*)(Y + (size_t)(m0 + ty*4 + q) * D_ + tx*4) = o;
    }
}

// ---------------- Kernel 2: fused energy -> softmax -> ctx -----------------
// grid (4 mtiles, 96 bh), 256 threads. 64 m-rows per block, 4 threads/row.
__global__ __launch_bounds__(256)
void attn_kernel(const float* __restrict__ Qd, const float* __restrict__ Kd,
                 const float* __restrict__ Vd, float* __restrict__ Ctx)
{
    __shared__ float S[M_][D_];    // 64 KB: Kd first, then reused for Vd
    const int mt = blockIdx.x;
    const int bh = blockIdx.y;
    const float* qd = Qd + (size_t)bh * M_ * D_;
    const float* kd = Kd + (size_t)bh * M_ * D_;
    const float* vd = Vd + (size_t)bh * M_ * D_;
    float* ctx = Ctx + (size_t)bh * M_ * D_;

    const int tid = threadIdx.x;
    const int r = tid >> 2, sub = tid & 3;   // row 0..63, sub-lane 0..3
    const int m = mt * 64 + r;

    // Qd row into registers
    float q[64];
    #pragma unroll
    for (int g = 0; g < 16; ++g) {
        const float4 t = ld4(qd + (size_t)m * D_ + g*4);
        q[4*g+0] = t.x; q[4*g+1] = t.y; q[4*g+2] = t.z; q[4*g+3] = t.w;
    }

    // stage Kd (swizzled: float4 group g stored at g^(k&3))
    #pragma unroll
    for (int it = 0; it < 16; ++it) {
        const int i = tid + it*256;         // float4 index, 4096 total
        const int k = i >> 4, g = i & 15;
        const float4 t = ld4(kd + (size_t)i * 4);
        *(float4*)(&S[k][(g ^ (k & 3)) * 4]) = t;
    }
    __syncthreads();

    // energy: e[kk] = Qd[m,:] . Kd[4*kk+sub,:]
    float e[64];
    #pragma unroll
    for (int kk = 0; kk < 64; ++kk) {
        const int k = kk*4 + sub;           // k&3 == sub
        float acc = 0.f;
        #pragma unroll
        for (int g = 0; g < 16; ++g) {
            const float4 t = ld4(&S[k][(g ^ sub) * 4]);
            acc = fmaf(q[4*g+0], t.x, acc);
            acc = fmaf(q[4*g+1], t.y, acc);
            acc = fmaf(q[4*g+2], t.z, acc);
            acc = fmaf(q[4*g+3], t.w, acc);
        }
        e[kk] = acc;
    }

    // row softmax across 64 regs x 4 sub-lanes
    float mx = e[0];
    #pragma unroll
    for (int kk = 1; kk < 64; ++kk) mx = fmaxf(mx, e[kk]);
    mx = fmaxf(mx, __shfl_xor(mx, 1));
    mx = fmaxf(mx, __shfl_xor(mx, 2));
    float sum = 0.f;
    #pragma unroll
    for (int kk = 0; kk < 64; ++kk) { e[kk] = __expf(e[kk] - mx); sum += e[kk]; }
    sum += __shfl_xor(sum, 1);
    sum += __shfl_xor(sum, 2);
    const float inv = 1.0f / sum;

    __syncthreads();   // everyone done reading Kd
    // stage Vd into the same LDS
    #pragma unroll
    for (int it = 0; it < 16; ++it) {
        const int i = tid + it*256;
        const int k = i >> 4, g = i & 15;
        const float4 t = ld4(vd + (size_t)i * 4);
        *(float4*)(&S[k][(g ^ (k & 3)) * 4]) = t;
    }
    __syncthreads();

    // ctx[m,:] += e[kk] * Vd[4*kk+sub,:]
    float c[64] = {};
    #pragma unroll
    for (int kk = 0; kk < 64; ++kk) {
        const int k = kk*4 + sub;
        const float a = e[kk];
        #pragma unroll
        for (int g = 0; g < 16; ++g) {
            const float4 t = ld4(&S[k][(g ^ sub) * 4]);
            c[4*g+0] = fmaf(a, t.x, c[4*g+0]);
            c[4*g+1] = fmaf(a, t.y, c[4*g+1]);
            c[4*g+2] = fmaf(a, t.z, c[4*g+2]);
            c[4*g+3] = fmaf(a, t.w, c[4*g+3]);
        }
    }
    // reduce partial ctx across the 4 sub-lanes of each row
    #pragma unroll
    for (int d = 0; d < 64; ++d) {
        c[d] += __shfl_xor(c[d], 1);
        c[d] += __shfl_xor(c[d], 2);
    }
    // each sub-lane writes 16 consecutive d's of its row
    #pragma unroll
    for (int gg = 0; gg < 4; ++gg) {
        const int d = sub*16 + gg*4;
        float4 o; o.x = c[d]*inv; o.y = c[d+1]*inv; o.z = c[d+2]*inv; o.w = c[d+3]*inv;
        *(float4*)(ctx + (size_t)m * D_ + d) = o;
    }
}

// ---------------- Kernel 3: x = Dct^T @ ctx --------------------------------
// grid (32 ntiles, 96 bh), 256 threads
__global__ __launch_bounds__(256)
void idct_kernel(const float* __restrict__ Dct, const float* __restrict__ Ctx,
                 float* __restrict__ Out)
{
    const int nt = blockIdx.x;   // 0..31 (64 rows of N)
    const int bh = blockIdx.y;
    const float* ctx = Ctx + (size_t)bh * M_ * D_;
    float* out = Out + (size_t)bh * N_ * D_;

    __shared__ float At[16][68];   // At[mk][n_local]
    __shared__ float Bs[16][64];   // Bs[mk][d]

    const int tid = threadIdx.x;
    const int tx = tid & 15, ty = tid >> 4;
    const int n0 = nt * 64;

    float acc[4][4] = {};

    for (int mt2 = 0; mt2 < M_/16; ++mt2) {
        const int mk0 = mt2 * 16;
        __syncthreads();
        // stage A: At[j][i] = Dct[(mk0+j)*N + n0+i]   (coalesced along i)
        {
            const int i = tid & 63;
            #pragma unroll
            for (int jj = 0; jj < 4; ++jj) {
                const int j = (tid >> 6) + jj*4;
                At[j][i] = Dct[(size_t)(mk0 + j) * N_ + n0 + i];
            }
        }
        // stage B: ctx tile is contiguous 1024 floats
        {
            const float4 t = ld4(ctx + (size_t)mk0 * D_ + tid * 4);
            const int j = tid >> 4, d0 = (tid & 15) * 4;
            *(float4*)(&Bs[j][d0]) = t;
        }
        __syncthreads();
        #pragma unroll
        for (int k = 0; k < 16; ++k) {
            const float4 av = ld4(&At[k][ty*4]);
            const float4 bv = ld4(&Bs[k][tx*4]);
            const float a[4]  = {av.x, av.y, av.z, av.w};
            const float bb[4] = {bv.x, bv.y, bv.z, bv.w};
            #pragma unroll
            for (int qq = 0; qq < 4; ++qq)
                #pragma unroll
                for (int p = 0; p < 4; ++p)
                    acc[qq][p] = fmaf(a[qq], bb[p], acc[qq][p]);
        }
    }
    #pragma unroll
    for (int qq = 0; qq < 4; ++qq) {
        float4 o; o.x = acc[qq][0]; o.y = acc[qq][1]; o.z = acc[qq][2]; o.w = acc[qq][3];
        *(float4*)(out + (size_t)(n0 + ty*4 + qq) * D_ + tx*4) = o;
    }
}

extern "C" void kernel_launch(void* const* d_in, const int* in_sizes, int n_in,
                              void* d_out, int out_size, void* d_ws, size_t ws_size,
                              hipStream_t stream) {
    const float* Q    = (const float*)d_in[0];
    const float* K    = (const float*)d_in[1];
    const float* V    = (const float*)d_in[2];
    const float* mask = (const float*)d_in[3];
    const float* Dct  = (const float*)d_in[4];
    float* out = (float*)d_out;

    const size_t per = (size_t)BH_ * M_ * D_;   // 1,572,864 floats
    float* ws  = (float*)d_ws;
    float* Qd  = ws;
    float* Kd  = Qd + per;
    float* Vd  = Kd + per;
    float* Ctx = Vd + per;

    dim3 g1(M_/64, BH_, 3);
    dct_qkv_kernel<<<g1, 256, 0, stream>>>(Q, K, V, mask, Dct, Qd, Kd, Vd);

    dim3 g2(M_/64, BH_);
    attn_kernel<<<g2, 256, 0, stream>>>(Qd, Kd, Vd, Ctx);

    dim3 g3(N_/64, BH_);
    idct_kernel<<<g3, 256, 0, stream>>>(Dct, Ctx, out);
}

// Round 2
// 306.852 us; speedup vs baseline: 1.4280x; 1.4280x over previous
//
#include <hip/hip_runtime.h>
#include <hip/hip_bf16.h>
#include <cstddef>

#define B_ 8
#define H_ 12
#define N_ 2048
#define D_ 64
#define M_ 256
#define BH_ (B_*H_)

typedef __attribute__((ext_vector_type(8))) short short8v;
typedef __attribute__((ext_vector_type(4))) float f32x4;

static __device__ __forceinline__ float4 ld4(const float* p){ return *(const float4*)p; }

static __device__ __forceinline__ unsigned short f2bf(float x){
    union { float f; unsigned int u; } v; v.f = x;
    unsigned int r = v.u + 0x7FFFu + ((v.u >> 16) & 1u);
    return (unsigned short)(r >> 16);
}
static __device__ __forceinline__ unsigned int pack2(float a, float b){
    return (unsigned int)f2bf(a) | ((unsigned int)f2bf(b) << 16);
}

// ---------------- K0b: Dct fp32 -> DctB bf16 [256][2048] + DctT bf16 [2048][256]
__global__ __launch_bounds__(256)
void dct_prep_kernel(const float* __restrict__ Dct, unsigned short* __restrict__ DctB,
                     unsigned short* __restrict__ DctT)
{
    __shared__ __align__(16) unsigned short T[64*72];
    const int n0 = blockIdx.x * 64, m0 = blockIdx.y * 64;
    const int tid = threadIdx.x;
    const int m = tid >> 2, ng = tid & 3;
    unsigned short h[16];
    #pragma unroll
    for (int j = 0; j < 4; ++j) {
        const float4 t = ld4(Dct + (size_t)(m0+m)*N_ + n0 + ng*16 + j*4);
        h[4*j+0]=f2bf(t.x); h[4*j+1]=f2bf(t.y); h[4*j+2]=f2bf(t.z); h[4*j+3]=f2bf(t.w);
    }
    unsigned int w[8];
    #pragma unroll
    for (int j = 0; j < 8; ++j) w[j] = (unsigned int)h[2*j] | ((unsigned int)h[2*j+1]<<16);
    unsigned short* db = DctB + (size_t)(m0+m)*N_ + n0 + ng*16;
    *(uint4*)db = *(uint4*)&w[0];
    *(uint4*)(db+8) = *(uint4*)&w[4];
    #pragma unroll
    for (int j = 0; j < 16; ++j) T[(ng*16+j)*72 + m] = h[j];
    __syncthreads();
    const int n = tid >> 2, mg = tid & 3;
    uint4 a  = *(uint4*)&T[n*72 + mg*16];
    uint4 b2 = *(uint4*)&T[n*72 + mg*16 + 8];
    unsigned short* dt = DctT + (size_t)(n0+n)*M_ + m0 + mg*16;
    *(uint4*)dt = a; *(uint4*)(dt+8) = b2;
}

// ---------------- K1: Qd/Kd/Vd = DctB @ (scaled/masked X), MFMA bf16 ----------
// grid (2 msplit, 96 bh, 3 tz), 128 threads (2 waves), tile 128m x 64d, BK=64
__global__ __launch_bounds__(128, 2)
void gemm_qkv(const float* __restrict__ Q, const float* __restrict__ K,
              const float* __restrict__ V, const float* __restrict__ mask,
              const unsigned short* __restrict__ DctB,
              float* __restrict__ Qd, float* __restrict__ Kd, float* __restrict__ Vd)
{
    __shared__ __align__(16) unsigned short Asw[128*64];  // 16 KB, rows 128 B, swz (r&7)<<4
    __shared__ __align__(16) unsigned short Bsw[64*64];   // 8 KB,  rows 128 B, swz ((d>>1)&7)<<4
    const int ms = blockIdx.x, bh = blockIdx.y, tz = blockIdx.z;
    const int b = bh / H_;
    const float scale = 0.35355339059327373f;
    const float* X; float* Y; float smul; int um;
    if (tz==0)      { X=Q; Y=Qd; smul=scale; um=0; }
    else if (tz==1) { X=K; Y=Kd; smul=scale; um=1; }
    else            { X=V; Y=Vd; smul=1.0f;  um=1; }
    X += (size_t)bh*N_*D_;
    Y += (size_t)bh*M_*D_ + (size_t)ms*128*D_;
    const int m0 = ms*128;

    const int tid  = threadIdx.x;
    const int lane = tid & 63, wave = tid >> 6;
    const int d0   = (tid & 31)*2, kgrp = tid >> 5;

    f32x4 acc[4][4];
    #pragma unroll
    for (int i = 0; i < 4; ++i)
        #pragma unroll
        for (int j = 0; j < 4; ++j) { acc[i][j].x=0.f; acc[i][j].y=0.f; acc[i][j].z=0.f; acc[i][j].w=0.f; }

    for (int step = 0; step < N_/64; ++step) {
        const int k0 = step*64;
        if (step) __syncthreads();
        // stage A (bf16 Dct rows, swizzled)
        {
            const int ch = tid & 7;
            #pragma unroll
            for (int rr = 0; rr < 8; ++rr) {
                const int r = (tid>>3) + rr*16;
                const uint4 v = *(const uint4*)(DctB + (size_t)(m0+r)*N_ + k0 + ch*8);
                *(uint4*)((char*)Asw + r*128 + ((ch*16) ^ ((r&7)<<4))) = v;
            }
        }
        // stage B: X fp32 [k][d] -> bf16 Bsw[d][k], scale+mask folded
        {
            const float* xp = X + (size_t)(k0 + kgrp*16)*D_ + d0;
            const float* mp = mask + (size_t)b*N_ + k0 + kgrp*16;
            float2 xa[16];
            #pragma unroll
            for (int kk = 0; kk < 16; ++kk) {
                float2 v = *(const float2*)(xp + kk*D_);
                float f = smul;
                if (um) f *= mp[kk];
                xa[kk].x = v.x*f; xa[kk].y = v.y*f;
            }
            #pragma unroll
            for (int j = 0; j < 4; ++j) {
                const int lk = kgrp*16 + j*4;
                uint2 w0, w1;
                w0.x = pack2(xa[4*j+0].x, xa[4*j+1].x);
                w0.y = pack2(xa[4*j+2].x, xa[4*j+3].x);
                w1.x = pack2(xa[4*j+0].y, xa[4*j+1].y);
                w1.y = pack2(xa[4*j+2].y, xa[4*j+3].y);
                *(uint2*)((char*)Bsw + d0*128     + ((lk*2) ^ (((d0>>1)&7)<<4)))     = w0;
                *(uint2*)((char*)Bsw + (d0+1)*128 + ((lk*2) ^ ((((d0+1)>>1)&7)<<4))) = w1;
            }
        }
        __syncthreads();
        #pragma unroll
        for (int kh = 0; kh < 2; ++kh) {
            const int colb = kh*64 + (lane>>4)*16;
            short8v a[4], bb[4];
            #pragma unroll
            for (int mf = 0; mf < 4; ++mf) {
                const int r = wave*64 + mf*16 + (lane&15);
                a[mf] = *(const short8v*)((char*)Asw + r*128 + (colb ^ ((r&7)<<4)));
            }
            #pragma unroll
            for (int nf = 0; nf < 4; ++nf) {
                const int r = nf*16 + (lane&15);
                bb[nf] = *(const short8v*)((char*)Bsw + r*128 + (colb ^ (((r>>1)&7)<<4)));
            }
            #pragma unroll
            for (int mf = 0; mf < 4; ++mf)
                #pragma unroll
                for (int nf = 0; nf < 4; ++nf)
                    acc[mf][nf] = __builtin_amdgcn_mfma_f32_16x16x32_bf16(a[mf], bb[nf], acc[mf][nf], 0, 0, 0);
        }
    }
    // epilogue: D layout col = lane&15 (d), row = (lane>>4)*4 + r (m)
    #pragma unroll
    for (int mf = 0; mf < 4; ++mf)
        #pragma unroll
        for (int nf = 0; nf < 4; ++nf)
            #pragma unroll
            for (int r = 0; r < 4; ++r) {
                const int m = wave*64 + mf*16 + (lane>>4)*4 + r;
                const int d = nf*16 + (lane&15);
                Y[(size_t)m*D_ + d] = acc[mf][nf][r];
            }
}

// ---------------- K2: fused energy -> softmax -> ctx (fp32), bf16 transposed out
__global__ __launch_bounds__(256)
void attn_kernel(const float* __restrict__ Qd, const float* __restrict__ Kd,
                 const float* __restrict__ Vd, unsigned short* __restrict__ CtxT)
{
    __shared__ __align__(16) float S[M_][D_];    // 64 KB
    const int mt = blockIdx.x;
    const int bh = blockIdx.y;
    const float* qd = Qd + (size_t)bh * M_ * D_;
    const float* kd = Kd + (size_t)bh * M_ * D_;
    const float* vd = Vd + (size_t)bh * M_ * D_;

    const int tid = threadIdx.x;
    const int r = tid >> 2, sub = tid & 3;
    const int m = mt * 64 + r;

    float q[64];
    #pragma unroll
    for (int g = 0; g < 16; ++g) {
        const float4 t = ld4(qd + (size_t)m * D_ + g*4);
        q[4*g+0] = t.x; q[4*g+1] = t.y; q[4*g+2] = t.z; q[4*g+3] = t.w;
    }

    #pragma unroll
    for (int it = 0; it < 16; ++it) {
        const int i = tid + it*256;
        const int k = i >> 4, g = i & 15;
        const float4 t = ld4(kd + (size_t)i * 4);
        *(float4*)(&S[k][(g ^ (k & 3)) * 4]) = t;
    }
    __syncthreads();

    float e[64];
    #pragma unroll
    for (int kk = 0; kk < 64; ++kk) {
        const int k = kk*4 + sub;
        float acc = 0.f;
        #pragma unroll
        for (int g = 0; g < 16; ++g) {
            const float4 t = ld4(&S[k][(g ^ sub) * 4]);
            acc = fmaf(q[4*g+0], t.x, acc);
            acc = fmaf(q[4*g+1], t.y, acc);
            acc = fmaf(q[4*g+2], t.z, acc);
            acc = fmaf(q[4*g+3], t.w, acc);
        }
        e[kk] = acc;
    }

    float mx = e[0];
    #pragma unroll
    for (int kk = 1; kk < 64; ++kk) mx = fmaxf(mx, e[kk]);
    mx = fmaxf(mx, __shfl_xor(mx, 1));
    mx = fmaxf(mx, __shfl_xor(mx, 2));
    float sum = 0.f;
    #pragma unroll
    for (int kk = 0; kk < 64; ++kk) { e[kk] = __expf(e[kk] - mx); sum += e[kk]; }
    sum += __shfl_xor(sum, 1);
    sum += __shfl_xor(sum, 2);
    const float inv = 1.0f / sum;

    __syncthreads();
    #pragma unroll
    for (int it = 0; it < 16; ++it) {
        const int i = tid + it*256;
        const int k = i >> 4, g = i & 15;
        const float4 t = ld4(vd + (size_t)i * 4);
        *(float4*)(&S[k][(g ^ (k & 3)) * 4]) = t;
    }
    __syncthreads();

    float c[64] = {};
    #pragma unroll
    for (int kk = 0; kk < 64; ++kk) {
        const int k = kk*4 + sub;
        const float a = e[kk];
        #pragma unroll
        for (int g = 0; g < 16; ++g) {
            const float4 t = ld4(&S[k][(g ^ sub) * 4]);
            c[4*g+0] = fmaf(a, t.x, c[4*g+0]);
            c[4*g+1] = fmaf(a, t.y, c[4*g+1]);
            c[4*g+2] = fmaf(a, t.z, c[4*g+2]);
            c[4*g+3] = fmaf(a, t.w, c[4*g+3]);
        }
    }
    #pragma unroll
    for (int d = 0; d < 64; ++d) {
        c[d] += __shfl_xor(c[d], 1);
        c[d] += __shfl_xor(c[d], 2);
    }

    // transposed bf16 output via LDS bounce (reuse S)
    __syncthreads();
    unsigned short* T = (unsigned short*)&S[0][0];   // [64 d][72 m] ushorts
    #pragma unroll
    for (int g = 0; g < 16; ++g) {
        const int d = sub*16 + g;
        T[d*72 + r] = f2bf(c[d]*inv);
    }
    __syncthreads();
    const int d2 = tid >> 2, mg = tid & 3;
    uint4 w0 = *(uint4*)&T[d2*72 + mg*16];
    uint4 w1 = *(uint4*)&T[d2*72 + mg*16 + 8];
    unsigned short* dst = CtxT + (size_t)bh*D_*M_ + (size_t)d2*M_ + mt*64 + mg*16;
    *(uint4*)dst = w0; *(uint4*)(dst+8) = w1;
}

// ---------------- K3: x = DctT @ ctx_t^T, MFMA bf16 ------------------------
// grid (16 ntile, 96 bh), 128 threads, tile 128n x 64d, K=256, BK=64
__global__ __launch_bounds__(128, 2)
void gemm_out(const unsigned short* __restrict__ DctT, const unsigned short* __restrict__ CtxT,
              float* __restrict__ Out)
{
    __shared__ __align__(16) unsigned short Asw[128*64];
    __shared__ __align__(16) unsigned short Bsw[64*64];
    const int nt = blockIdx.x, bh = blockIdx.y;
    const int n0 = nt*128;
    const unsigned short* ct = CtxT + (size_t)bh*D_*M_;
    float* out = Out + (size_t)bh*N_*D_;
    const int tid = threadIdx.x;
    const int lane = tid & 63, wave = tid >> 6;

    f32x4 acc[4][4];
    #pragma unroll
    for (int i = 0; i < 4; ++i)
        #pragma unroll
        for (int j = 0; j < 4; ++j) { acc[i][j].x=0.f; acc[i][j].y=0.f; acc[i][j].z=0.f; acc[i][j].w=0.f; }

    for (int step = 0; step < 4; ++step) {
        const int k0 = step*64;
        if (step) __syncthreads();
        const int ch = tid & 7;
        #pragma unroll
        for (int rr = 0; rr < 8; ++rr) {
            const int r = (tid>>3) + rr*16;
            const uint4 v = *(const uint4*)(DctT + (size_t)(n0+r)*M_ + k0 + ch*8);
            *(uint4*)((char*)Asw + r*128 + ((ch*16) ^ ((r&7)<<4))) = v;
        }
        #pragma unroll
        for (int rr = 0; rr < 4; ++rr) {
            const int d = (tid>>3) + rr*16;
            const uint4 v = *(const uint4*)(ct + (size_t)d*M_ + k0 + ch*8);
            *(uint4*)((char*)Bsw + d*128 + ((ch*16) ^ (((d>>1)&7)<<4))) = v;
        }
        __syncthreads();
        #pragma unroll
        for (int kh = 0; kh < 2; ++kh) {
            const int colb = kh*64 + (lane>>4)*16;
            short8v a[4], bb[4];
            #pragma unroll
            for (int mf = 0; mf < 4; ++mf) {
                const int r = wave*64 + mf*16 + (lane&15);
                a[mf] = *(const short8v*)((char*)Asw + r*128 + (colb ^ ((r&7)<<4)));
            }
            #pragma unroll
            for (int nf = 0; nf < 4; ++nf) {
                const int r = nf*16 + (lane&15);
                bb[nf] = *(const short8v*)((char*)Bsw + r*128 + (colb ^ (((r>>1)&7)<<4)));
            }
            #pragma unroll
            for (int mf = 0; mf < 4; ++mf)
                #pragma unroll
                for (int nf = 0; nf < 4; ++nf)
                    acc[mf][nf] = __builtin_amdgcn_mfma_f32_16x16x32_bf16(a[mf], bb[nf], acc[mf][nf], 0, 0, 0);
        }
    }
    #pragma unroll
    for (int mf = 0; mf < 4; ++mf)
        #pragma unroll
        for (int nf = 0; nf < 4; ++nf)
            #pragma unroll
            for (int r = 0; r < 4; ++r) {
                const int n = n0 + wave*64 + mf*16 + (lane>>4)*4 + r;
                const int d = nf*16 + (lane&15);
                out[(size_t)n*D_ + d] = acc[mf][nf][r];
            }
}

extern "C" void kernel_launch(void* const* d_in, const int* in_sizes, int n_in,
                              void* d_out, int out_size, void* d_ws, size_t ws_size,
                              hipStream_t stream) {
    const float* Q    = (const float*)d_in[0];
    const float* K    = (const float*)d_in[1];
    const float* V    = (const float*)d_in[2];
    const float* mask = (const float*)d_in[3];
    const float* Dct  = (const float*)d_in[4];
    float* out = (float*)d_out;

    const size_t per = (size_t)BH_ * M_ * D_;          // 1,572,864
    float* wsf = (float*)d_ws;
    float* Qd = wsf;
    float* Kd = Qd + per;
    float* Vd = Kd + per;
    unsigned short* CtxT = (unsigned short*)(Vd + per);  // per ushorts
    unsigned short* DctB = CtxT + per;                   // 524288
    unsigned short* DctT = DctB + (size_t)M_ * N_;       // 524288

    dct_prep_kernel<<<dim3(N_/64, M_/64), 256, 0, stream>>>(Dct, DctB, DctT);
    gemm_qkv<<<dim3(2, BH_, 3), 128, 0, stream>>>(Q, K, V, mask, DctB, Qd, Kd, Vd);
    attn_kernel<<<dim3(M_/64, BH_), 256, 0, stream>>>(Qd, Kd, Vd, CtxT);
    gemm_out<<<dim3(N_/128, BH_), 128, 0, stream>>>(DctT, CtxT, out);
}

// Round 3
// 140.927 us; speedup vs baseline: 3.1093x; 2.1774x over previous
//
#include <hip/hip_runtime.h>
#include <hip/hip_bf16.h>
#include <cstddef>

#define B_ 8
#define H_ 12
#define N_ 2048
#define D_ 64
#define M_ 256
#define BH_ (B_*H_)

typedef __attribute__((ext_vector_type(8))) short short8v;
typedef __attribute__((ext_vector_type(4))) float f32x4;
typedef __attribute__((address_space(3))) unsigned int lds_u32_t;
typedef __attribute__((address_space(1))) const unsigned int glb_u32_t;

static __device__ __forceinline__ float4 ld4(const float* p){ return *(const float4*)p; }

static __device__ __forceinline__ unsigned short f2bf(float x){
    union { float f; unsigned int u; } v; v.f = x;
    unsigned int r = v.u + 0x7FFFu + ((v.u >> 16) & 1u);
    return (unsigned short)(r >> 16);
}
static __device__ __forceinline__ unsigned int pack2(float a, float b){
    return (unsigned int)f2bf(a) | ((unsigned int)f2bf(b) << 16);
}
static __device__ __forceinline__ void gload_lds16(const void* g, void* l){
    __builtin_amdgcn_global_load_lds((glb_u32_t*)g, (lds_u32_t*)l, 16, 0, 0);
}

// ---------------- K0b: Dct fp32 -> DctB bf16 [256][2048] + DctT bf16 [2048][256]
__global__ __launch_bounds__(256)
void dct_prep_kernel(const float* __restrict__ Dct, unsigned short* __restrict__ DctB,
                     unsigned short* __restrict__ DctT)
{
    __shared__ __align__(16) unsigned short T[64*72];
    const int n0 = blockIdx.x * 64, m0 = blockIdx.y * 64;
    const int tid = threadIdx.x;
    const int m = tid >> 2, ng = tid & 3;
    unsigned short h[16];
    #pragma unroll
    for (int j = 0; j < 4; ++j) {
        const float4 t = ld4(Dct + (size_t)(m0+m)*N_ + n0 + ng*16 + j*4);
        h[4*j+0]=f2bf(t.x); h[4*j+1]=f2bf(t.y); h[4*j+2]=f2bf(t.z); h[4*j+3]=f2bf(t.w);
    }
    unsigned int w[8];
    #pragma unroll
    for (int j = 0; j < 8; ++j) w[j] = (unsigned int)h[2*j] | ((unsigned int)h[2*j+1]<<16);
    unsigned short* db = DctB + (size_t)(m0+m)*N_ + n0 + ng*16;
    *(uint4*)db = *(uint4*)&w[0];
    *(uint4*)(db+8) = *(uint4*)&w[4];
    #pragma unroll
    for (int j = 0; j < 16; ++j) T[(ng*16+j)*72 + m] = h[j];
    __syncthreads();
    const int n = tid >> 2, mg = tid & 3;
    uint4 a  = *(uint4*)&T[n*72 + mg*16];
    uint4 b2 = *(uint4*)&T[n*72 + mg*16 + 8];
    unsigned short* dt = DctT + (size_t)(n0+n)*M_ + m0 + mg*16;
    *(uint4*)dt = a; *(uint4*)(dt+8) = b2;
}

// ---------------- K1: Qd/Kd/Vd = DctB @ (scaled/masked X), MFMA bf16, dbuf ----
// grid (2 msplit, 96 bh, 3 tz), 256 threads (4 waves), tile 128m x 64d, BK=64
__global__ __launch_bounds__(256, 3)
void gemm_qkv(const float* __restrict__ Q, const float* __restrict__ K,
              const float* __restrict__ V, const float* __restrict__ mask,
              const unsigned short* __restrict__ DctB,
              float* __restrict__ Qd, float* __restrict__ Kd, float* __restrict__ Vd)
{
    __shared__ __align__(16) unsigned short Asw[2][128*64];  // 2 x 16 KB, row 128 B, swz (r&7)<<4
    __shared__ __align__(16) unsigned short Bsw[2][64*64];   // 2 x 8 KB,  row 128 B, swz ((d>>1)&7)<<4
    const int ms = blockIdx.x, bh = blockIdx.y, tz = blockIdx.z;
    const int b = bh / H_;
    const float scale = 0.35355339059327373f;
    const float* X; float* Y; float smul; int um;
    if (tz==0)      { X=Q; Y=Qd; smul=scale; um=0; }
    else if (tz==1) { X=K; Y=Kd; smul=scale; um=1; }
    else            { X=V; Y=Vd; smul=1.0f;  um=1; }
    X += (size_t)bh*N_*D_;
    Y += (size_t)bh*M_*D_ + (size_t)ms*128*D_;
    const int m0 = ms*128;

    const int tid  = threadIdx.x;
    const int lane = tid & 63, wave = tid >> 6;
    // B staging: thread covers 8 k-rows (kseg) x 2 d (d0, d0+1)
    const int d0   = (tid & 31)*2, kseg = tid >> 5;
    const int bswz = ((d0>>1)&7)<<4;
    // A staging (global_load_lds): per instr, lane -> row R+(lane>>3), slot lane&7.
    // Source chunk pre-swizzled: c = slot ^ (r&7) = (lane&7) ^ (lane>>3 & 7) since R%8==0.
    const int ar = lane >> 3, as = lane & 7;
    const int ac = as ^ ar;   // chunk index in source row

    f32x4 acc[2][4];
    #pragma unroll
    for (int i = 0; i < 2; ++i)
        #pragma unroll
        for (int j = 0; j < 4; ++j) { acc[i][j].x=0.f; acc[i][j].y=0.f; acc[i][j].z=0.f; acc[i][j].w=0.f; }

    float2 xr[8];
    float  mr[8];

    // per-lane constant source base for A staging
    const unsigned short* abase = DctB + (size_t)(m0 + wave*32 + ar) * N_ + ac*8;

    #define LOAD_B(k0) do {                                                   \
        const float* xp = X + (size_t)((k0) + kseg*8) * D_ + d0;              \
        const float* mp = mask + (size_t)b*N_ + (k0) + kseg*8;                \
        _Pragma("unroll")                                                     \
        for (int i = 0; i < 8; ++i) { xr[i] = *(const float2*)(xp + i*D_); mr[i] = mp[i]; } \
    } while(0)

    #define STAGE_A(bufi, k0) do {                                            \
        _Pragma("unroll")                                                     \
        for (int i = 0; i < 4; ++i) {                                         \
            const int R = wave*32 + i*8;                                      \
            gload_lds16(abase + (size_t)(i*8)*N_ + (k0),                      \
                        (char*)&Asw[bufi][0] + R*128);                        \
        }                                                                     \
    } while(0)

    #define WRITE_B(bufi) do {                                                \
        float fa[8], fb[8];                                                   \
        _Pragma("unroll")                                                     \
        for (int i = 0; i < 8; ++i) {                                         \
            const float f = um ? smul*mr[i] : smul;                           \
            fa[i] = xr[i].x * f; fb[i] = xr[i].y * f;                         \
        }                                                                     \
        uint4 w0, w1;                                                         \
        w0.x=pack2(fa[0],fa[1]); w0.y=pack2(fa[2],fa[3]);                     \
        w0.z=pack2(fa[4],fa[5]); w0.w=pack2(fa[6],fa[7]);                     \
        w1.x=pack2(fb[0],fb[1]); w1.y=pack2(fb[2],fb[3]);                     \
        w1.z=pack2(fb[4],fb[5]); w1.w=pack2(fb[6],fb[7]);                     \
        *(uint4*)((char*)&Bsw[bufi][0] + d0*128     + ((kseg*16) ^ bswz)) = w0; \
        *(uint4*)((char*)&Bsw[bufi][0] + (d0+1)*128 + ((kseg*16) ^ bswz)) = w1; \
    } while(0)

    #define COMPUTE(bufi) do {                                                \
        _Pragma("unroll")                                                     \
        for (int kh = 0; kh < 2; ++kh) {                                      \
            const int colb = kh*64 + (lane>>4)*16;                            \
            short8v a[2], bb[4];                                              \
            _Pragma("unroll")                                                 \
            for (int mf = 0; mf < 2; ++mf) {                                  \
                const int r = wave*32 + mf*16 + (lane&15);                    \
                a[mf] = *(const short8v*)((char*)&Asw[bufi][0] + r*128 + (colb ^ ((r&7)<<4))); \
            }                                                                 \
            _Pragma("unroll")                                                 \
            for (int nf = 0; nf < 4; ++nf) {                                  \
                const int rr = nf*16 + (lane&15);                             \
                bb[nf] = *(const short8v*)((char*)&Bsw[bufi][0] + rr*128 + (colb ^ (((rr>>1)&7)<<4))); \
            }                                                                 \
            _Pragma("unroll")                                                 \
            for (int mf = 0; mf < 2; ++mf)                                    \
                _Pragma("unroll")                                             \
                for (int nf = 0; nf < 4; ++nf)                                \
                    acc[mf][nf] = __builtin_amdgcn_mfma_f32_16x16x32_bf16(a[mf], bb[nf], acc[mf][nf], 0, 0, 0); \
        }                                                                     \
    } while(0)

    // prologue: stage tile 0
    LOAD_B(0);
    STAGE_A(0, 0);
    WRITE_B(0);
    __syncthreads();

    int buf = 0;
    for (int t = 0; t < 32; ++t) {
        if (t < 31) {
            LOAD_B((t+1)*64);          // issue global loads early (T14)
            STAGE_A(buf^1, (t+1)*64);  // async global->LDS
        }
        COMPUTE(buf);                  // MFMAs hide the loads above
        if (t < 31) WRITE_B(buf^1);    // cvt+pack+ds_write after compute
        __syncthreads();
        buf ^= 1;
    }

    // epilogue: D layout col = lane&15 (d), row = (lane>>4)*4 + r (m)
    #pragma unroll
    for (int mf = 0; mf < 2; ++mf)
        #pragma unroll
        for (int nf = 0; nf < 4; ++nf)
            #pragma unroll
            for (int r = 0; r < 4; ++r) {
                const int m = wave*32 + mf*16 + (lane>>4)*4 + r;
                const int d = nf*16 + (lane&15);
                Y[(size_t)m*D_ + d] = acc[mf][nf][r];
            }
    #undef LOAD_B
    #undef STAGE_A
    #undef WRITE_B
    #undef COMPUTE
}

// ---------------- K2: fused energy -> softmax -> ctx (fp32), bf16 transposed out
__global__ __launch_bounds__(256)
void attn_kernel(const float* __restrict__ Qd, const float* __restrict__ Kd,
                 const float* __restrict__ Vd, unsigned short* __restrict__ CtxT)
{
    __shared__ __align__(16) float S[M_][D_];    // 64 KB
    const int mt = blockIdx.x;
    const int bh = blockIdx.y;
    const float* qd = Qd + (size_t)bh * M_ * D_;
    const float* kd = Kd + (size_t)bh * M_ * D_;
    const float* vd = Vd + (size_t)bh * M_ * D_;

    const int tid = threadIdx.x;
    const int r = tid >> 2, sub = tid & 3;
    const int m = mt * 64 + r;

    float q[64];
    #pragma unroll
    for (int g = 0; g < 16; ++g) {
        const float4 t = ld4(qd + (size_t)m * D_ + g*4);
        q[4*g+0] = t.x; q[4*g+1] = t.y; q[4*g+2] = t.z; q[4*g+3] = t.w;
    }

    #pragma unroll
    for (int it = 0; it < 16; ++it) {
        const int i = tid + it*256;
        const int k = i >> 4, g = i & 15;
        const float4 t = ld4(kd + (size_t)i * 4);
        *(float4*)(&S[k][(g ^ (k & 3)) * 4]) = t;
    }
    __syncthreads();

    float e[64];
    #pragma unroll
    for (int kk = 0; kk < 64; ++kk) {
        const int k = kk*4 + sub;
        float acc = 0.f;
        #pragma unroll
        for (int g = 0; g < 16; ++g) {
            const float4 t = ld4(&S[k][(g ^ sub) * 4]);
            acc = fmaf(q[4*g+0], t.x, acc);
            acc = fmaf(q[4*g+1], t.y, acc);
            acc = fmaf(q[4*g+2], t.z, acc);
            acc = fmaf(q[4*g+3], t.w, acc);
        }
        e[kk] = acc;
    }

    float mx = e[0];
    #pragma unroll
    for (int kk = 1; kk < 64; ++kk) mx = fmaxf(mx, e[kk]);
    mx = fmaxf(mx, __shfl_xor(mx, 1));
    mx = fmaxf(mx, __shfl_xor(mx, 2));
    float sum = 0.f;
    #pragma unroll
    for (int kk = 0; kk < 64; ++kk) { e[kk] = __expf(e[kk] - mx); sum += e[kk]; }
    sum += __shfl_xor(sum, 1);
    sum += __shfl_xor(sum, 2);
    const float inv = 1.0f / sum;

    __syncthreads();
    #pragma unroll
    for (int it = 0; it < 16; ++it) {
        const int i = tid + it*256;
        const int k = i >> 4, g = i & 15;
        const float4 t = ld4(vd + (size_t)i * 4);
        *(float4*)(&S[k][(g ^ (k & 3)) * 4]) = t;
    }
    __syncthreads();

    float c[64] = {};
    #pragma unroll
    for (int kk = 0; kk < 64; ++kk) {
        const int k = kk*4 + sub;
        const float a = e[kk];
        #pragma unroll
        for (int g = 0; g < 16; ++g) {
            const float4 t = ld4(&S[k][(g ^ sub) * 4]);
            c[4*g+0] = fmaf(a, t.x, c[4*g+0]);
            c[4*g+1] = fmaf(a, t.y, c[4*g+1]);
            c[4*g+2] = fmaf(a, t.z, c[4*g+2]);
            c[4*g+3] = fmaf(a, t.w, c[4*g+3]);
        }
    }
    #pragma unroll
    for (int d = 0; d < 64; ++d) {
        c[d] += __shfl_xor(c[d], 1);
        c[d] += __shfl_xor(c[d], 2);
    }

    __syncthreads();
    unsigned short* T = (unsigned short*)&S[0][0];   // [64 d][72 m] ushorts
    #pragma unroll
    for (int g = 0; g < 16; ++g) {
        const int d = sub*16 + g;
        T[d*72 + r] = f2bf(c[d]*inv);
    }
    __syncthreads();
    const int d2 = tid >> 2, mg = tid & 3;
    uint4 w0 = *(uint4*)&T[d2*72 + mg*16];
    uint4 w1 = *(uint4*)&T[d2*72 + mg*16 + 8];
    unsigned short* dst = CtxT + (size_t)bh*D_*M_ + (size_t)d2*M_ + mt*64 + mg*16;
    *(uint4*)dst = w0; *(uint4*)(dst+8) = w1;
}

// ---------------- K3: x = DctT @ ctx_t^T, MFMA bf16 ------------------------
__global__ __launch_bounds__(128, 2)
void gemm_out(const unsigned short* __restrict__ DctT, const unsigned short* __restrict__ CtxT,
              float* __restrict__ Out)
{
    __shared__ __align__(16) unsigned short Asw[128*64];
    __shared__ __align__(16) unsigned short Bsw[64*64];
    const int nt = blockIdx.x, bh = blockIdx.y;
    const int n0 = nt*128;
    const unsigned short* ct = CtxT + (size_t)bh*D_*M_;
    float* out = Out + (size_t)bh*N_*D_;
    const int tid = threadIdx.x;
    const int lane = tid & 63, wave = tid >> 6;

    f32x4 acc[4][4];
    #pragma unroll
    for (int i = 0; i < 4; ++i)
        #pragma unroll
        for (int j = 0; j < 4; ++j) { acc[i][j].x=0.f; acc[i][j].y=0.f; acc[i][j].z=0.f; acc[i][j].w=0.f; }

    for (int step = 0; step < 4; ++step) {
        const int k0 = step*64;
        if (step) __syncthreads();
        const int ch = tid & 7;
        #pragma unroll
        for (int rr = 0; rr < 8; ++rr) {
            const int r = (tid>>3) + rr*16;
            const uint4 v = *(const uint4*)(DctT + (size_t)(n0+r)*M_ + k0 + ch*8);
            *(uint4*)((char*)Asw + r*128 + ((ch*16) ^ ((r&7)<<4))) = v;
        }
        #pragma unroll
        for (int rr = 0; rr < 4; ++rr) {
            const int d = (tid>>3) + rr*16;
            const uint4 v = *(const uint4*)(ct + (size_t)d*M_ + k0 + ch*8);
            *(uint4*)((char*)Bsw + d*128 + ((ch*16) ^ (((d>>1)&7)<<4))) = v;
        }
        __syncthreads();
        #pragma unroll
        for (int kh = 0; kh < 2; ++kh) {
            const int colb = kh*64 + (lane>>4)*16;
            short8v a[4], bb[4];
            #pragma unroll
            for (int mf = 0; mf < 4; ++mf) {
                const int r = wave*64 + mf*16 + (lane&15);
                a[mf] = *(const short8v*)((char*)Asw + r*128 + (colb ^ ((r&7)<<4)));
            }
            #pragma unroll
            for (int nf = 0; nf < 4; ++nf) {
                const int r = nf*16 + (lane&15);
                bb[nf] = *(const short8v*)((char*)Bsw + r*128 + (colb ^ (((r>>1)&7)<<4)));
            }
            #pragma unroll
            for (int mf = 0; mf < 4; ++mf)
                #pragma unroll
                for (int nf = 0; nf < 4; ++nf)
                    acc[mf][nf] = __builtin_amdgcn_mfma_f32_16x16x32_bf16(a[mf], bb[nf], acc[mf][nf], 0, 0, 0);
        }
    }
    #pragma unroll
    for (int mf = 0; mf < 4; ++mf)
        #pragma unroll
        for (int nf = 0; nf < 4; ++nf)
            #pragma unroll
            for (int r = 0; r < 4; ++r) {
                const int n = n0 + wave*64 + mf*16 + (lane>>4)*4 + r;
                const int d = nf*16 + (lane&15);
                out[(size_t)n*D_ + d] = acc[mf][nf][r];
            }
}

extern "C" void kernel_launch(void* const* d_in, const int* in_sizes, int n_in,
                              void* d_out, int out_size, void* d_ws, size_t ws_size,
                              hipStream_t stream) {
    const float* Q    = (const float*)d_in[0];
    const float* K    = (const float*)d_in[1];
    const float* V    = (const float*)d_in[2];
    const float* mask = (const float*)d_in[3];
    const float* Dct  = (const float*)d_in[4];
    float* out = (float*)d_out;

    const size_t per = (size_t)BH_ * M_ * D_;          // 1,572,864
    float* wsf = (float*)d_ws;
    float* Qd = wsf;
    float* Kd = Qd + per;
    float* Vd = Kd + per;
    unsigned short* CtxT = (unsigned short*)(Vd + per);  // per ushorts
    unsigned short* DctB = CtxT + per;                   // 524288
    unsigned short* DctT = DctB + (size_t)M_ * N_;       // 524288

    dct_prep_kernel<<<dim3(N_/64, M_/64), 256, 0, stream>>>(Dct, DctB, DctT);
    gemm_qkv<<<dim3(2, BH_, 3), 256, 0, stream>>>(Q, K, V, mask, DctB, Qd, Kd, Vd);
    attn_kernel<<<dim3(M_/64, BH_), 256, 0, stream>>>(Qd, Kd, Vd, CtxT);
    gemm_out<<<dim3(N_/128, BH_), 128, 0, stream>>>(DctT, CtxT, out);
}